// Round 22
// baseline (131.746 us; speedup 1.0000x reference)
//
#include <hip/hip_runtime.h>

typedef unsigned short u16;
typedef unsigned int u32;
typedef __bf16 bf16x8 __attribute__((ext_vector_type(8)));
typedef float f32x4 __attribute__((ext_vector_type(4)));
typedef u16 u16x8 __attribute__((ext_vector_type(8)));
typedef u16 u16x4 __attribute__((ext_vector_type(4)));
typedef u32 u32x4 __attribute__((ext_vector_type(4)));

#define NH 16
#define DKK 64
#define SQ 2048
#define DD 1024

#define AS1 __attribute__((address_space(1)))
#define AS3 __attribute__((address_space(3)))

// softmax scale folded with log2(e): (1/8) * 1.44269504
#define QSCALE 0.1803368925f

#define WAIT4 do { asm volatile("s_waitcnt vmcnt(4)" ::: "memory"); \
                   __builtin_amdgcn_sched_barrier(0); } while (0)
#define WAIT3 do { asm volatile("s_waitcnt vmcnt(3)" ::: "memory"); \
                   __builtin_amdgcn_sched_barrier(0); } while (0)
#define WAIT0 do { asm volatile("s_waitcnt vmcnt(0)" ::: "memory"); \
                   __builtin_amdgcn_sched_barrier(0); } while (0)
#define LWAIT0 do { asm volatile("s_waitcnt lgkmcnt(0)" ::: "memory"); \
                    __builtin_amdgcn_sched_barrier(0); } while (0)
#define BAR   __builtin_amdgcn_s_barrier()

__device__ inline u16 f2bf(float f) {
  union { float f; u32 u; } v; v.f = f;
  u32 u = v.u;
  u += 0x7FFFu + ((u >> 16) & 1u);
  return (u16)(u >> 16);
}

__device__ __forceinline__ u32 cvtpk(float lo, float hi) {
  u32 r;
  asm("v_cvt_pk_bf16_f32 %0, %1, %2" : "=v"(r) : "v"(lo), "v"(hi));
  return r;
}

__device__ inline u16x8 cvt8(const float* p) {
  float4 a = *(const float4*)p;
  float4 b = *(const float4*)(p + 4);
  u16x8 v;
  v[0] = f2bf(a.x); v[1] = f2bf(a.y); v[2] = f2bf(a.z); v[3] = f2bf(a.w);
  v[4] = f2bf(b.x); v[5] = f2bf(b.y); v[6] = f2bf(b.z); v[7] = f2bf(b.w);
  return v;
}

// direct global->LDS async copy, 16B/lane; LDS dest = wave-uniform base + lane*16
__device__ __forceinline__ void gload16(const u16* g, u16* l) {
  __builtin_amdgcn_global_load_lds((const AS1 u32*)(const void*)g,
                                   (AS3 u32*)(void*)l, 16, 0, 0);
}

// ---------------- prep: f32->bf16 convert (x, Wo) + weight transpose, one launch ----------------
__global__ __launch_bounds__(256) void prep_kernel(const float* __restrict__ x,
                                                   u16* __restrict__ xb,
                                                   const float* __restrict__ Wo,
                                                   u16* __restrict__ Wob,
                                                   const float* __restrict__ Wq,
                                                   const float* __restrict__ Wk,
                                                   const float* __restrict__ Wv,
                                                   u16* __restrict__ WT) {
  __shared__ u16 sm[64][72];
  int bid = blockIdx.x;
  int tid = threadIdx.x;
  if (bid < 2560) {   // bulk convert
    const float* src; u16* dst; size_t base;
    if (bid < 2048) { src = x;  dst = xb;  base = (size_t)bid * 2048; }
    else            { src = Wo; dst = Wob; base = (size_t)(bid - 2048) * 2048; }
    size_t off = base + (size_t)tid * 8;
    *(u16x8*)&dst[off] = cvt8(&src[off]);
    return;
  }
  int wid = bid - 2560;
  int t = wid >> 8;
  int rem = wid & 255;
  int h = rem >> 4;
  int d0 = (rem & 15) * 64;
  const float* src = (t == 0) ? Wq : (t == 1) ? Wk : Wv;
  for (int j = 0; j < 2; ++j) {
    int idx = tid + j * 256;
    int r = idx >> 3;
    int c0 = (idx & 7) * 8;
    *(u16x8*)&sm[r][c0] = cvt8(&src[(h * DD + d0 + r) * DKK + c0]);
  }
  __syncthreads();
  for (int j = 0; j < 2; ++j) {
    int idx = tid + j * 256;
    int r2 = idx >> 3;
    int c0 = (idx & 7) * 8;
    u16x8 vv;
    for (int i = 0; i < 8; ++i) vv[i] = sm[c0 + i][r2];
    int n = t * 1024 + h * 64 + r2;
    *(u16x8*)&WT[n * DD + d0 + c0] = vv;
  }
}

// ---------------- 128x128-tile bf16 GEMM: 3 buffers, 2-deep prefetch, ONE barrier/K-step ----------------
// Per iter J: WAIT(tile J landed) -> BAR -> STAGE(J+2) -> 16 MFMA on buf J%3.
// Single barrier is safe: all waves finished iter J-1 (so buf (J+2)%3 is free) and
// all waves drained their tile-J DMAs (per-wave vmcnt(4)) before the barrier.
// Staging ledger: prologue tiles 0,1; iter kt stages kt+2 (kt=0..29) -> all 32 tiles staged.
__global__ __launch_bounds__(256) void gemm128(const u16* __restrict__ A,
                                               const u16* __restrict__ Bm,
                                               u16* __restrict__ o0,
                                               u16* __restrict__ o1,
                                               u16* __restrict__ o2) {
  __shared__ u16 As[3][128 * 32];
  __shared__ u16 Bs[3][128 * 32];
  const int K = 1024;
  int m0 = blockIdx.x * 128;
  int n0 = blockIdx.y * 128;
  int tid = threadIdx.x;
  int w = tid >> 6, l = tid & 63;
  int lg = l >> 4, lr = l & 15;
  int wr = w >> 1, wc = w & 1;

  int srow = w * 32 + (l >> 2);           // staging row (each gload covers 16 rows)
  int sg = (l & 3) ^ ((l >> 3) & 3);      // pre-swizzled source granule
  const u16* gA = A + (size_t)(m0 + srow) * K + sg * 8;
  const u16* gB = Bm + (size_t)(n0 + srow) * K + sg * 8;
  int gsw = (lr >> 1) & 3;                // read-side swizzle key

  #define GSTAGE(buf, k0)                              \
    do {                                               \
      gload16(gA + (k0), &As[buf][w * 1024]);          \
      gload16(gA + (k0) + 16 * K, &As[buf][w * 1024 + 512]); \
      gload16(gB + (k0), &Bs[buf][w * 1024]);          \
      gload16(gB + (k0) + 16 * K, &Bs[buf][w * 1024 + 512]); \
    } while (0)

  #define GCOMP(BC)                                                            \
    do {                                                                       \
      bf16x8 a[4], b[4];                                                       \
      _Pragma("unroll")                                                        \
      for (int m = 0; m < 4; ++m)                                              \
        a[m] = *(const bf16x8*)&As[BC][(wr * 64 + m * 16 + lr) * 32 + ((lg ^ gsw) * 8)]; \
      _Pragma("unroll")                                                        \
      for (int n = 0; n < 4; ++n)                                              \
        b[n] = *(const bf16x8*)&Bs[BC][(wc * 64 + n * 16 + lr) * 32 + ((lg ^ gsw) * 8)]; \
      _Pragma("unroll")                                                        \
      for (int m = 0; m < 4; ++m)                                              \
        _Pragma("unroll")                                                      \
        for (int n = 0; n < 4; ++n)                                            \
          acc[m][n] = __builtin_amdgcn_mfma_f32_16x16x32_bf16(a[m], b[n], acc[m][n], 0, 0, 0); \
    } while (0)

  f32x4 acc[4][4] = {};
  GSTAGE(0, 0);
  GSTAGE(1, 32);
  for (int kt = 0; kt < 30; kt += 3) {
    WAIT4; BAR; GSTAGE(2, (kt + 2) * 32); GCOMP(0);
    WAIT4; BAR; GSTAGE(0, (kt + 3) * 32); GCOMP(1);
    WAIT4; BAR; GSTAGE(1, (kt + 4) * 32); GCOMP(2);   // kt=27 stages tile 31 (the r21 bug: was guarded out)
  }
  WAIT4; BAR; GCOMP(0);    // tile 30 (buf 0)
  WAIT0; BAR; GCOMP(1);    // tile 31 (buf 1)
  #undef GSTAGE
  #undef GCOMP

  {
    int t = n0 >> 10;
    int h = (((n0 & 1023) + wc * 64) >> 6);
    int bq = m0 >> 11;
    int sbase = (m0 & 2047) + wr * 64 + lg * 4;
    if (t < 2) {
      float sc = (t == 0) ? QSCALE : 1.0f;   // fold softmax scale*log2e into Q
      u16* o = (t == 0) ? o0 : o1;
      u16* op = o + (size_t)(bq * NH + h) * SQ * DKK;
      #pragma unroll
      for (int m = 0; m < 4; ++m)
        #pragma unroll
        for (int n = 0; n < 4; ++n)
          #pragma unroll
          for (int rr = 0; rr < 4; ++rr)
            op[(size_t)(sbase + m * 16 + rr) * DKK + n * 16 + lr] = f2bf(acc[m][n][rr] * sc);
    } else {
      // V^T with sigma-permuted S: S block base + (m>>1)*32 + lg*8 + (m&1)*4 + rr
      u16* op = o2 + (size_t)(bq * NH + h) * DKK * SQ;
      int Sb = (m0 & 2047) + wr * 64;
      #pragma unroll
      for (int m = 0; m < 4; ++m)
        #pragma unroll
        for (int n = 0; n < 4; ++n) {
          u16x4 vv;
          #pragma unroll
          for (int rr = 0; rr < 4; ++rr) vv[rr] = f2bf(acc[m][n][rr]);
          *(u16x4*)&op[(size_t)(n * 16 + lr) * SQ + Sb + (m >> 1) * 32 + lg * 8 + (m & 1) * 4] = vv;
        }
    }
  }
}

// ---------------- Wo GEMM: 128x64 tile, 2 blocks/CU, BK=32 dbuf counted-vmcnt (r18 proven) ----------------
__global__ __launch_bounds__(256) void gemm_wo(const u16* __restrict__ A,
                                               const u16* __restrict__ Bm,
                                               float* __restrict__ of) {
  __shared__ u16 As[2][128 * 32];
  __shared__ u16 Bs[2][64 * 32];
  const int K = 1024;
  int m0 = blockIdx.x * 128;
  int n0 = blockIdx.y * 64;
  int tid = threadIdx.x;
  int w = tid >> 6, l = tid & 63;
  int lg = l >> 4, lr = l & 15;
  int wr = w >> 1, wc = w & 1;

  int sg = (l & 3) ^ ((l >> 3) & 3);      // pre-swizzled source granule
  const u16* gA = A + (size_t)(m0 + w * 32 + (l >> 2)) * K + sg * 8;
  const u16* gB = Bm + (size_t)(n0 + w * 16 + (l >> 2)) * K + sg * 8;
  int gsw = (lr >> 1) & 3;                // read-side swizzle key

  #define WSTAGE(buf, k0)                              \
    do {                                               \
      gload16(gA + (k0), &As[buf][w * 1024]);          \
      gload16(gA + (k0) + 16 * K, &As[buf][w * 1024 + 512]); \
      gload16(gB + (k0), &Bs[buf][w * 512]);           \
    } while (0)

  f32x4 acc[4][2] = {};
  WSTAGE(0, 0);
  for (int kt = 0; kt < 32; ++kt) {
    int buf = kt & 1;
    if (kt < 31) { WSTAGE(buf ^ 1, (kt + 1) * 32); WAIT3; }
    else         { WAIT0; }
    BAR;
    bf16x8 a[4], b[2];
    #pragma unroll
    for (int m = 0; m < 4; ++m)
      a[m] = *(const bf16x8*)&As[buf][(wr * 64 + m * 16 + lr) * 32 + ((lg ^ gsw) * 8)];
    #pragma unroll
    for (int n = 0; n < 2; ++n)
      b[n] = *(const bf16x8*)&Bs[buf][(wc * 32 + n * 16 + lr) * 32 + ((lg ^ gsw) * 8)];
    #pragma unroll
    for (int m = 0; m < 4; ++m)
      #pragma unroll
      for (int n = 0; n < 2; ++n)
        acc[m][n] = __builtin_amdgcn_mfma_f32_16x16x32_bf16(a[m], b[n], acc[m][n], 0, 0, 0);
    BAR;
  }
  #undef WSTAGE

  int mbase = m0 + wr * 64 + lg * 4;
  int nbase = n0 + wc * 32 + lr;
  #pragma unroll
  for (int m = 0; m < 4; ++m)
    #pragma unroll
    for (int n = 0; n < 2; ++n)
      #pragma unroll
      for (int rr = 0; rr < 4; ++rr)
        of[(size_t)(mbase + m * 16 + rr) * 1024 + nbase + n * 16] = acc[m][n][rr];
}

// ---------------- Flash attention v16: 3 buffers, 2-deep prefetch, ONE barrier/tile ----------------
// Iter j: WAIT(tile j) -> BAR -> STAGE(j+2) -> QK(j) + PV(j-1) + V(j)->regs + softmax ->
// lgkmcnt(0). Single barrier safe (see gemm comment); V-reads drained before next overwrite.
__global__ __launch_bounds__(256) void attn_kernel(const u16* __restrict__ Q,
                                                   const u16* __restrict__ Kg,
                                                   const u16* __restrict__ Vt,
                                                   u16* __restrict__ Cc) {
  __shared__ u16 Ks[3][64 * 64];
  __shared__ u16 Vs[3][64 * 64];   // [dk][kv-sigma]
  int bh = blockIdx.x;             // bh fastest -> round-robin spreads strips
  int y = blockIdx.y;
  int a = y & 7, bsel = y >> 3;
  int s = (bsel == 0) ? 2 * a : (bsel == 1) ? 2 * a + 1
        : (bsel == 2) ? 30 - 2 * a : 31 - 2 * a;   // per-CU sums balanced
  int tid = threadIdx.x;
  int w = tid >> 6, l = tid & 63;
  int lg = l >> 4, lr = l & 15;
  const u16* Qp = Q + (size_t)bh * SQ * DKK;
  const u16* Kp = Kg + (size_t)bh * SQ * DKK;
  const u16* Vp = Vt + (size_t)bh * DKK * SQ;
  int b = bh >> 4, h = bh & 15;

  int lrow8 = l >> 3;
  int swz = (l & 7) ^ lrow8;
  int r7 = lr & 7;
  const u16* kSrc0 = Kp + (size_t)(w * 16 + lrow8) * DKK + swz * 8;
  const u16* kSrc1 = Kp + (size_t)(w * 16 + 8 + lrow8) * DKK + swz * 8;
  const u16* vSrc0 = Vp + (size_t)(w * 16 + lrow8) * SQ + swz * 8;
  const u16* vSrc1 = Vp + (size_t)(w * 16 + 8 + lrow8) * SQ + swz * 8;

  #define STAGE(buf, j0)                                                  \
    do {                                                                  \
      gload16(kSrc0 + (size_t)(j0) * DKK, &Ks[buf][(w * 16) * 64]);       \
      gload16(kSrc1 + (size_t)(j0) * DKK, &Ks[buf][(w * 16 + 8) * 64]);   \
      gload16(vSrc0 + (j0), &Vs[buf][(w * 16) * 64]);                     \
      gload16(vSrc1 + (j0), &Vs[buf][(w * 16 + 8) * 64]);                 \
    } while (0)

  // Q loads issued first; their completion folds into the first vmcnt wait
  int qrow = s * 64 + w * 16 + lr;
  bf16x8 qf0 = *(const bf16x8*)&Qp[(size_t)qrow * DKK + lg * 8];
  bf16x8 qf1 = *(const bf16x8*)&Qp[(size_t)qrow * DKK + 32 + lg * 8];

  STAGE(0, 0);
  if (s >= 1) STAGE(1, 64);

  f32x4 o[4] = {};
  float lpart = 0.f, suPrev = 0.f;
  union { u16x8 u; bf16x8 v; } zz;
  #pragma unroll
  for (int i = 0; i < 8; ++i) zz.u[i] = 0;
  bf16x8 paPrev0 = zz.v, paPrev1 = zz.v;
  bf16x8 vPrev0[4], vPrev1[4];
  #pragma unroll
  for (int n = 0; n < 4; ++n) { vPrev0[n] = zz.v; vPrev1[n] = zz.v; }

  int cur = 0;
  for (int jt = 0; jt <= s; ++jt) {
    if (jt < s) WAIT4; else WAIT0;         // tile jt's 4 loads landed (all waves pre-BAR)
    BAR;                                   // single barrier per tile
    if (jt + 2 <= s) {
      int bs = (cur == 0) ? 2 : cur - 1;   // (cur+2)%3
      STAGE(bs, (jt + 2) * 64);
    }

    float p[16];
    __builtin_amdgcn_s_setprio(1);
    // QK(jt)
    #pragma unroll
    for (int c = 0; c < 4; ++c) {
      int R = c * 16 + lr;
      const u16* kr = &Ks[cur][R * 64];
      bf16x8 k0 = *(const bf16x8*)&kr[(lg ^ r7) * 8];
      bf16x8 k1 = *(const bf16x8*)&kr[((4 + lg) ^ r7) * 8];
      f32x4 z = {};
      z = __builtin_amdgcn_mfma_f32_16x16x32_bf16(k0, qf0, z, 0, 0, 0);
      z = __builtin_amdgcn_mfma_f32_16x16x32_bf16(k1, qf1, z, 0, 0, 0);
      #pragma unroll
      for (int rr = 0; rr < 4; ++rr) p[c * 4 + rr] = z[rr];
    }
    // PV(jt-1): independent of softmax(jt) -> fills MFMA pipe
    #pragma unroll
    for (int n = 0; n < 4; ++n) {
      o[n] = __builtin_amdgcn_mfma_f32_16x16x32_bf16(paPrev0, vPrev0[n], o[n], 0, 0, 0);
      o[n] = __builtin_amdgcn_mfma_f32_16x16x32_bf16(paPrev1, vPrev1[n], o[n], 0, 0, 0);
    }
    __builtin_amdgcn_s_setprio(0);
    lpart += suPrev;
    // V(jt) -> regs (consumed next iter; latency fully hidden)
    #pragma unroll
    for (int n = 0; n < 4; ++n) {
      int R2 = n * 16 + lr;
      vPrev0[n] = *(const bf16x8*)&Vs[cur][R2 * 64 + ((lg ^ r7) * 8)];
      vPrev1[n] = *(const bf16x8*)&Vs[cur][R2 * 64 + (((4 + lg) ^ r7) * 8)];
    }
    if (jt == s) {  // causal mask on diagonal tile
      int j0 = jt * 64;
      #pragma unroll
      for (int c = 0; c < 4; ++c)
        #pragma unroll
        for (int rr = 0; rr < 4; ++rr) {
          int kv = j0 + c * 16 + lg * 4 + rr;
          if (kv > qrow) p[c * 4 + rr] = -1e30f;
        }
    }
    // raw exp2 softmax (shift cancels exactly in o/l)
    float su = 0.f;
    #pragma unroll
    for (int i = 0; i < 16; ++i) { p[i] = exp2f(p[i]); su += p[i]; }
    suPrev = su;
    // P -> bf16 A-frags in registers (sigma k-permutation)
    union { u32x4 w; bf16x8 v; } pk0, pk1;
    pk0.w[0] = cvtpk(p[0],  p[1]);
    pk0.w[1] = cvtpk(p[2],  p[3]);
    pk0.w[2] = cvtpk(p[4],  p[5]);
    pk0.w[3] = cvtpk(p[6],  p[7]);
    pk1.w[0] = cvtpk(p[8],  p[9]);
    pk1.w[1] = cvtpk(p[10], p[11]);
    pk1.w[2] = cvtpk(p[12], p[13]);
    pk1.w[3] = cvtpk(p[14], p[15]);
    paPrev0 = pk0.v;
    paPrev1 = pk1.v;
    LWAIT0;                                // V ds_reads drained before next iter's overwrite
    cur = (cur == 2) ? 0 : cur + 1;
  }

  // epilogue: final PV(s) + its sum
  #pragma unroll
  for (int n = 0; n < 4; ++n) {
    o[n] = __builtin_amdgcn_mfma_f32_16x16x32_bf16(paPrev0, vPrev0[n], o[n], 0, 0, 0);
    o[n] = __builtin_amdgcn_mfma_f32_16x16x32_bf16(paPrev1, vPrev1[n], o[n], 0, 0, 0);
  }
  lpart += suPrev;

  float lsum = lpart;
  lsum += __shfl_xor(lsum, 16, 64);
  lsum += __shfl_xor(lsum, 32, 64);
  float lrow[4];
  #pragma unroll
  for (int rr = 0; rr < 4; ++rr) lrow[rr] = __shfl(lsum, lg * 4 + rr, 64);
  int srow = s * 64 + w * 16 + lg * 4;
  #pragma unroll
  for (int n = 0; n < 4; ++n)
    #pragma unroll
    for (int rr = 0; rr < 4; ++rr) {
      float val = o[n][rr] / lrow[rr];
      Cc[((size_t)(b * SQ + srow + rr)) * DD + h * DKK + n * 16 + lr] = f2bf(val);
    }
  #undef STAGE
}

extern "C" void kernel_launch(void* const* d_in, const int* in_sizes, int n_in,
                              void* d_out, int out_size, void* d_ws, size_t ws_size,
                              hipStream_t stream) {
  (void)in_sizes; (void)n_in; (void)out_size; (void)ws_size;
  const float* x  = (const float*)d_in[0];
  const float* Wq = (const float*)d_in[1];
  const float* Wk = (const float*)d_in[2];
  const float* Wv = (const float*)d_in[3];
  const float* Wo = (const float*)d_in[4];
  float* out = (float*)d_out;
  u16* ws = (u16*)d_ws;
  u16* WT  = ws;                    // 3,145,728 elems
  u16* Qb  = WT + 3145728;          // 4,194,304
  u16* Kb  = Qb + 4194304;          // 4,194,304
  u16* Vb  = Kb + 4194304;          // 4,194,304 (B,H,dk,S-sigma)
  u16* XC  = Vb + 4194304;          // 4,194,304 — xb (bf16 x), later aliased as Cc
  u16* Wob = XC + 4194304;          // 1,048,576

  hipLaunchKernelGGL(prep_kernel, dim3(3328), dim3(256), 0, stream, x, XC, Wo, Wob, Wq, Wk, Wv, WT);
  hipLaunchKernelGGL(gemm128, dim3(32, 24), dim3(256), 0, stream, XC, WT, Qb, Kb, Vb);
  hipLaunchKernelGGL(attn_kernel, dim3(32, 32), dim3(256), 0, stream, Qb, Kb, Vb, XC);
  hipLaunchKernelGGL(gemm_wo, dim3(32, 16), dim3(256), 0, stream, XC, Wob, out);
}

// Round 23
// 106.694 us; speedup vs baseline: 1.2348x; 1.2348x over previous
//
#include <hip/hip_runtime.h>

typedef unsigned short u16;
typedef unsigned int u32;
typedef __bf16 bf16x8 __attribute__((ext_vector_type(8)));
typedef float f32x4 __attribute__((ext_vector_type(4)));
typedef u16 u16x8 __attribute__((ext_vector_type(8)));
typedef u16 u16x4 __attribute__((ext_vector_type(4)));
typedef u32 u32x4 __attribute__((ext_vector_type(4)));

#define NH 16
#define DKK 64
#define SQ 2048
#define DD 1024

#define AS1 __attribute__((address_space(1)))
#define AS3 __attribute__((address_space(3)))

// softmax scale folded with log2(e): (1/8) * 1.44269504
#define QSCALE 0.1803368925f

#define WAIT4 do { asm volatile("s_waitcnt vmcnt(4)" ::: "memory"); \
                   __builtin_amdgcn_sched_barrier(0); } while (0)
#define WAIT3 do { asm volatile("s_waitcnt vmcnt(3)" ::: "memory"); \
                   __builtin_amdgcn_sched_barrier(0); } while (0)
#define WAIT0 do { asm volatile("s_waitcnt vmcnt(0)" ::: "memory"); \
                   __builtin_amdgcn_sched_barrier(0); } while (0)
#define LWAIT0 do { asm volatile("s_waitcnt lgkmcnt(0)" ::: "memory"); \
                    __builtin_amdgcn_sched_barrier(0); } while (0)
#define BAR   __builtin_amdgcn_s_barrier()

__device__ inline u16 f2bf(float f) {
  union { float f; u32 u; } v; v.f = f;
  u32 u = v.u;
  u += 0x7FFFu + ((u >> 16) & 1u);
  return (u16)(u >> 16);
}

__device__ __forceinline__ u32 cvtpk(float lo, float hi) {
  u32 r;
  asm("v_cvt_pk_bf16_f32 %0, %1, %2" : "=v"(r) : "v"(lo), "v"(hi));
  return r;
}

__device__ inline u16x8 cvt8(const float* p) {
  float4 a = *(const float4*)p;
  float4 b = *(const float4*)(p + 4);
  u16x8 v;
  v[0] = f2bf(a.x); v[1] = f2bf(a.y); v[2] = f2bf(a.z); v[3] = f2bf(a.w);
  v[4] = f2bf(b.x); v[5] = f2bf(b.y); v[6] = f2bf(b.z); v[7] = f2bf(b.w);
  return v;
}

// direct global->LDS async copy, 16B/lane; LDS dest = wave-uniform base + lane*16
__device__ __forceinline__ void gload16(const u16* g, u16* l) {
  __builtin_amdgcn_global_load_lds((const AS1 u32*)(const void*)g,
                                   (AS3 u32*)(void*)l, 16, 0, 0);
}

// ---------------- prep: f32->bf16 convert (x, Wo) + weight transpose, one launch ----------------
__global__ __launch_bounds__(256) void prep_kernel(const float* __restrict__ x,
                                                   u16* __restrict__ xb,
                                                   const float* __restrict__ Wo,
                                                   u16* __restrict__ Wob,
                                                   const float* __restrict__ Wq,
                                                   const float* __restrict__ Wk,
                                                   const float* __restrict__ Wv,
                                                   u16* __restrict__ WT) {
  __shared__ u16 sm[64][72];
  int bid = blockIdx.x;
  int tid = threadIdx.x;
  if (bid < 2560) {   // bulk convert
    const float* src; u16* dst; size_t base;
    if (bid < 2048) { src = x;  dst = xb;  base = (size_t)bid * 2048; }
    else            { src = Wo; dst = Wob; base = (size_t)(bid - 2048) * 2048; }
    size_t off = base + (size_t)tid * 8;
    *(u16x8*)&dst[off] = cvt8(&src[off]);
    return;
  }
  int wid = bid - 2560;
  int t = wid >> 8;
  int rem = wid & 255;
  int h = rem >> 4;
  int d0 = (rem & 15) * 64;
  const float* src = (t == 0) ? Wq : (t == 1) ? Wk : Wv;
  for (int j = 0; j < 2; ++j) {
    int idx = tid + j * 256;
    int r = idx >> 3;
    int c0 = (idx & 7) * 8;
    *(u16x8*)&sm[r][c0] = cvt8(&src[(h * DD + d0 + r) * DKK + c0]);
  }
  __syncthreads();
  for (int j = 0; j < 2; ++j) {
    int idx = tid + j * 256;
    int r2 = idx >> 3;
    int c0 = (idx & 7) * 8;
    u16x8 vv;
    for (int i = 0; i < 8; ++i) vv[i] = sm[c0 + i][r2];
    int n = t * 1024 + h * 64 + r2;
    *(u16x8*)&WT[n * DD + d0 + c0] = vv;
  }
}

// ---------------- 128x128-tile bf16 GEMM, BK=32 dbuf, counted-vmcnt (round-16 proven) ----------------
__global__ __launch_bounds__(256) void gemm128(const u16* __restrict__ A,
                                               const u16* __restrict__ Bm,
                                               u16* __restrict__ o0,
                                               u16* __restrict__ o1,
                                               u16* __restrict__ o2) {
  __shared__ u16 As[2][128 * 32];
  __shared__ u16 Bs[2][128 * 32];
  const int K = 1024;
  int m0 = blockIdx.x * 128;
  int n0 = blockIdx.y * 128;
  int tid = threadIdx.x;
  int w = tid >> 6, l = tid & 63;
  int lg = l >> 4, lr = l & 15;
  int wr = w >> 1, wc = w & 1;

  int srow = w * 32 + (l >> 2);           // staging row (each gload covers 16 rows)
  int sg = (l & 3) ^ ((l >> 3) & 3);      // pre-swizzled source granule
  const u16* gA = A + (size_t)(m0 + srow) * K + sg * 8;
  const u16* gB = Bm + (size_t)(n0 + srow) * K + sg * 8;
  int gsw = (lr >> 1) & 3;                // read-side swizzle key

  #define GSTAGE(buf, k0)                              \
    do {                                               \
      gload16(gA + (k0), &As[buf][w * 1024]);          \
      gload16(gA + (k0) + 16 * K, &As[buf][w * 1024 + 512]); \
      gload16(gB + (k0), &Bs[buf][w * 1024]);          \
      gload16(gB + (k0) + 16 * K, &Bs[buf][w * 1024 + 512]); \
    } while (0)

  f32x4 acc[4][4] = {};
  GSTAGE(0, 0);
  for (int kt = 0; kt < 32; ++kt) {
    int buf = kt & 1;
    if (kt < 31) { GSTAGE(buf ^ 1, (kt + 1) * 32); WAIT4; }
    else         { WAIT0; }
    BAR;                                   // all waves' current-tile loads landed
    bf16x8 a[4], b[4];
    #pragma unroll
    for (int m = 0; m < 4; ++m)
      a[m] = *(const bf16x8*)&As[buf][(wr * 64 + m * 16 + lr) * 32 + ((lg ^ gsw) * 8)];
    #pragma unroll
    for (int n = 0; n < 4; ++n)
      b[n] = *(const bf16x8*)&Bs[buf][(wc * 64 + n * 16 + lr) * 32 + ((lg ^ gsw) * 8)];
    #pragma unroll
    for (int m = 0; m < 4; ++m)
      #pragma unroll
      for (int n = 0; n < 4; ++n)
        acc[m][n] = __builtin_amdgcn_mfma_f32_16x16x32_bf16(a[m], b[n], acc[m][n], 0, 0, 0);
    BAR;                                   // all waves done reading buf
  }
  #undef GSTAGE

  {
    int t = n0 >> 10;
    int h = (((n0 & 1023) + wc * 64) >> 6);
    int bq = m0 >> 11;
    int sbase = (m0 & 2047) + wr * 64 + lg * 4;
    if (t < 2) {
      float sc = (t == 0) ? QSCALE : 1.0f;   // fold softmax scale*log2e into Q
      u16* o = (t == 0) ? o0 : o1;
      u16* op = o + (size_t)(bq * NH + h) * SQ * DKK;
      #pragma unroll
      for (int m = 0; m < 4; ++m)
        #pragma unroll
        for (int n = 0; n < 4; ++n)
          #pragma unroll
          for (int rr = 0; rr < 4; ++rr)
            op[(size_t)(sbase + m * 16 + rr) * DKK + n * 16 + lr] = f2bf(acc[m][n][rr] * sc);
    } else {
      // V^T with sigma-permuted S: S block base + (m>>1)*32 + lg*8 + (m&1)*4 + rr
      u16* op = o2 + (size_t)(bq * NH + h) * DKK * SQ;
      int Sb = (m0 & 2047) + wr * 64;
      #pragma unroll
      for (int m = 0; m < 4; ++m)
        #pragma unroll
        for (int n = 0; n < 4; ++n) {
          u16x4 vv;
          #pragma unroll
          for (int rr = 0; rr < 4; ++rr) vv[rr] = f2bf(acc[m][n][rr]);
          *(u16x4*)&op[(size_t)(n * 16 + lr) * SQ + Sb + (m >> 1) * 32 + lg * 8 + (m & 1) * 4] = vv;
        }
    }
  }
}

// ---------------- Wo GEMM: 128x64 tile, 2 blocks/CU, BK=32 dbuf counted-vmcnt (r18 proven) ----------------
__global__ __launch_bounds__(256) void gemm_wo(const u16* __restrict__ A,
                                               const u16* __restrict__ Bm,
                                               float* __restrict__ of) {
  __shared__ u16 As[2][128 * 32];
  __shared__ u16 Bs[2][64 * 32];
  const int K = 1024;
  int m0 = blockIdx.x * 128;
  int n0 = blockIdx.y * 64;
  int tid = threadIdx.x;
  int w = tid >> 6, l = tid & 63;
  int lg = l >> 4, lr = l & 15;
  int wr = w >> 1, wc = w & 1;

  int sg = (l & 3) ^ ((l >> 3) & 3);      // pre-swizzled source granule
  const u16* gA = A + (size_t)(m0 + w * 32 + (l >> 2)) * K + sg * 8;
  const u16* gB = Bm + (size_t)(n0 + w * 16 + (l >> 2)) * K + sg * 8;
  int gsw = (lr >> 1) & 3;                // read-side swizzle key

  #define WSTAGE(buf, k0)                              \
    do {                                               \
      gload16(gA + (k0), &As[buf][w * 1024]);          \
      gload16(gA + (k0) + 16 * K, &As[buf][w * 1024 + 512]); \
      gload16(gB + (k0), &Bs[buf][w * 512]);           \
    } while (0)

  f32x4 acc[4][2] = {};
  WSTAGE(0, 0);
  for (int kt = 0; kt < 32; ++kt) {
    int buf = kt & 1;
    if (kt < 31) { WSTAGE(buf ^ 1, (kt + 1) * 32); WAIT3; }
    else         { WAIT0; }
    BAR;
    bf16x8 a[4], b[2];
    #pragma unroll
    for (int m = 0; m < 4; ++m)
      a[m] = *(const bf16x8*)&As[buf][(wr * 64 + m * 16 + lr) * 32 + ((lg ^ gsw) * 8)];
    #pragma unroll
    for (int n = 0; n < 2; ++n)
      b[n] = *(const bf16x8*)&Bs[buf][(wc * 32 + n * 16 + lr) * 32 + ((lg ^ gsw) * 8)];
    #pragma unroll
    for (int m = 0; m < 4; ++m)
      #pragma unroll
      for (int n = 0; n < 2; ++n)
        acc[m][n] = __builtin_amdgcn_mfma_f32_16x16x32_bf16(a[m], b[n], acc[m][n], 0, 0, 0);
    BAR;
  }
  #undef WSTAGE

  int mbase = m0 + wr * 64 + lg * 4;
  int nbase = n0 + wc * 32 + lr;
  #pragma unroll
  for (int m = 0; m < 4; ++m)
    #pragma unroll
    for (int n = 0; n < 2; ++n)
      #pragma unroll
      for (int rr = 0; rr < 4; ++rr)
        of[(size_t)(mbase + m * 16 + rr) * 1024 + nbase + n * 16] = acc[m][n][rr];
}

// ---------------- Flash attention v15: PV deferred one tile (round-20 proven) ----------------
// Iter j: QK(j) MFMA + PV(j-1) MFMA (independent of softmax(j)) share the pipe while
// the VALU does softmax(j). V(j) copied LDS->regs (consumed next iter -> latency hidden).
__global__ __launch_bounds__(256) void attn_kernel(const u16* __restrict__ Q,
                                                   const u16* __restrict__ Kg,
                                                   const u16* __restrict__ Vt,
                                                   u16* __restrict__ Cc) {
  __shared__ u16 Ks[2][64 * 64];
  __shared__ u16 Vs[2][64 * 64];   // [dk][kv-sigma]
  int bh = blockIdx.x;             // bh fastest -> round-robin spreads strips
  int y = blockIdx.y;
  int a = y & 7, bsel = y >> 3;
  int s = (bsel == 0) ? 2 * a : (bsel == 1) ? 2 * a + 1
        : (bsel == 2) ? 30 - 2 * a : 31 - 2 * a;   // per-CU sums balanced
  int tid = threadIdx.x;
  int w = tid >> 6, l = tid & 63;
  int lg = l >> 4, lr = l & 15;
  const u16* Qp = Q + (size_t)bh * SQ * DKK;
  const u16* Kp = Kg + (size_t)bh * SQ * DKK;
  const u16* Vp = Vt + (size_t)bh * DKK * SQ;
  int b = bh >> 4, h = bh & 15;

  int lrow8 = l >> 3;
  int swz = (l & 7) ^ lrow8;
  int r7 = lr & 7;
  const u16* kSrc0 = Kp + (size_t)(w * 16 + lrow8) * DKK + swz * 8;
  const u16* kSrc1 = Kp + (size_t)(w * 16 + 8 + lrow8) * DKK + swz * 8;
  const u16* vSrc0 = Vp + (size_t)(w * 16 + lrow8) * SQ + swz * 8;
  const u16* vSrc1 = Vp + (size_t)(w * 16 + 8 + lrow8) * SQ + swz * 8;

  #define STAGE(buf, j0)                                                  \
    do {                                                                  \
      gload16(kSrc0 + (size_t)(j0) * DKK, &Ks[buf][(w * 16) * 64]);       \
      gload16(kSrc1 + (size_t)(j0) * DKK, &Ks[buf][(w * 16 + 8) * 64]);   \
      gload16(vSrc0 + (j0), &Vs[buf][(w * 16) * 64]);                     \
      gload16(vSrc1 + (j0), &Vs[buf][(w * 16 + 8) * 64]);                 \
    } while (0)

  // Q loads issued before staging so their completion folds into the first vmcnt wait
  int qrow = s * 64 + w * 16 + lr;
  bf16x8 qf0 = *(const bf16x8*)&Qp[(size_t)qrow * DKK + lg * 8];
  bf16x8 qf1 = *(const bf16x8*)&Qp[(size_t)qrow * DKK + 32 + lg * 8];

  STAGE(0, 0);

  f32x4 o[4] = {};
  float lpart = 0.f, suPrev = 0.f;
  union { u16x8 u; bf16x8 v; } zz;
  #pragma unroll
  for (int i = 0; i < 8; ++i) zz.u[i] = 0;
  bf16x8 paPrev0 = zz.v, paPrev1 = zz.v;
  bf16x8 vPrev0[4], vPrev1[4];
  #pragma unroll
  for (int n = 0; n < 4; ++n) { vPrev0[n] = zz.v; vPrev1[n] = zz.v; }

  for (int jt = 0; jt <= s; ++jt) {
    int cur = jt & 1;
    if (jt < s) { STAGE(cur ^ 1, (jt + 1) * 64); WAIT4; }
    else        { WAIT0; }
    BAR;                                   // all waves' tile-jt loads landed

    float p[16];
    __builtin_amdgcn_s_setprio(1);
    // QK(jt)
    #pragma unroll
    for (int c = 0; c < 4; ++c) {
      int R = c * 16 + lr;
      const u16* kr = &Ks[cur][R * 64];
      bf16x8 k0 = *(const bf16x8*)&kr[(lg ^ r7) * 8];
      bf16x8 k1 = *(const bf16x8*)&kr[((4 + lg) ^ r7) * 8];
      f32x4 z = {};
      z = __builtin_amdgcn_mfma_f32_16x16x32_bf16(k0, qf0, z, 0, 0, 0);
      z = __builtin_amdgcn_mfma_f32_16x16x32_bf16(k1, qf1, z, 0, 0, 0);
      #pragma unroll
      for (int rr = 0; rr < 4; ++rr) p[c * 4 + rr] = z[rr];
    }
    // PV(jt-1): independent of softmax(jt) -> fills MFMA pipe
    #pragma unroll
    for (int n = 0; n < 4; ++n) {
      o[n] = __builtin_amdgcn_mfma_f32_16x16x32_bf16(paPrev0, vPrev0[n], o[n], 0, 0, 0);
      o[n] = __builtin_amdgcn_mfma_f32_16x16x32_bf16(paPrev1, vPrev1[n], o[n], 0, 0, 0);
    }
    __builtin_amdgcn_s_setprio(0);
    lpart += suPrev;
    // V(jt) -> regs (consumed next iter; latency fully hidden)
    #pragma unroll
    for (int n = 0; n < 4; ++n) {
      int R2 = n * 16 + lr;
      vPrev0[n] = *(const bf16x8*)&Vs[cur][R2 * 64 + ((lg ^ r7) * 8)];
      vPrev1[n] = *(const bf16x8*)&Vs[cur][R2 * 64 + (((4 + lg) ^ r7) * 8)];
    }
    if (jt == s) {  // causal mask on diagonal tile
      int j0 = jt * 64;
      #pragma unroll
      for (int c = 0; c < 4; ++c)
        #pragma unroll
        for (int rr = 0; rr < 4; ++rr) {
          int kv = j0 + c * 16 + lg * 4 + rr;
          if (kv > qrow) p[c * 4 + rr] = -1e30f;
        }
    }
    // raw exp2 softmax (shift cancels exactly in o/l)
    float su = 0.f;
    #pragma unroll
    for (int i = 0; i < 16; ++i) { p[i] = exp2f(p[i]); su += p[i]; }
    suPrev = su;
    // P -> bf16 A-frags in registers (sigma k-permutation)
    union { u32x4 w; bf16x8 v; } pk0, pk1;
    pk0.w[0] = cvtpk(p[0],  p[1]);
    pk0.w[1] = cvtpk(p[2],  p[3]);
    pk0.w[2] = cvtpk(p[4],  p[5]);
    pk0.w[3] = cvtpk(p[6],  p[7]);
    pk1.w[0] = cvtpk(p[8],  p[9]);
    pk1.w[1] = cvtpk(p[10], p[11]);
    pk1.w[2] = cvtpk(p[12], p[13]);
    pk1.w[3] = cvtpk(p[14], p[15]);
    paPrev0 = pk0.v;
    paPrev1 = pk1.v;
    LWAIT0;                                // V ds_reads must land before staging overwrites
    BAR;                                   // all waves done reading buf cur
  }

  // epilogue: final PV(s) + its sum
  #pragma unroll
  for (int n = 0; n < 4; ++n) {
    o[n] = __builtin_amdgcn_mfma_f32_16x16x32_bf16(paPrev0, vPrev0[n], o[n], 0, 0, 0);
    o[n] = __builtin_amdgcn_mfma_f32_16x16x32_bf16(paPrev1, vPrev1[n], o[n], 0, 0, 0);
  }
  lpart += suPrev;

  float lsum = lpart;
  lsum += __shfl_xor(lsum, 16, 64);
  lsum += __shfl_xor(lsum, 32, 64);
  float lrow[4];
  #pragma unroll
  for (int rr = 0; rr < 4; ++rr) lrow[rr] = __shfl(lsum, lg * 4 + rr, 64);
  int srow = s * 64 + w * 16 + lg * 4;
  #pragma unroll
  for (int n = 0; n < 4; ++n)
    #pragma unroll
    for (int rr = 0; rr < 4; ++rr) {
      float val = o[n][rr] / lrow[rr];
      Cc[((size_t)(b * SQ + srow + rr)) * DD + h * DKK + n * 16 + lr] = f2bf(val);
    }
  #undef STAGE
}

extern "C" void kernel_launch(void* const* d_in, const int* in_sizes, int n_in,
                              void* d_out, int out_size, void* d_ws, size_t ws_size,
                              hipStream_t stream) {
  (void)in_sizes; (void)n_in; (void)out_size; (void)ws_size;
  const float* x  = (const float*)d_in[0];
  const float* Wq = (const float*)d_in[1];
  const float* Wk = (const float*)d_in[2];
  const float* Wv = (const float*)d_in[3];
  const float* Wo = (const float*)d_in[4];
  float* out = (float*)d_out;
  u16* ws = (u16*)d_ws;
  u16* WT  = ws;                    // 3,145,728 elems
  u16* Qb  = WT + 3145728;          // 4,194,304
  u16* Kb  = Qb + 4194304;          // 4,194,304
  u16* Vb  = Kb + 4194304;          // 4,194,304 (B,H,dk,S-sigma)
  u16* XC  = Vb + 4194304;          // 4,194,304 — xb (bf16 x), later aliased as Cc
  u16* Wob = XC + 4194304;          // 1,048,576

  hipLaunchKernelGGL(prep_kernel, dim3(3328), dim3(256), 0, stream, x, XC, Wo, Wob, Wq, Wk, Wv, WT);
  hipLaunchKernelGGL(gemm128, dim3(32, 24), dim3(256), 0, stream, XC, WT, Qb, Kb, Vb);
  hipLaunchKernelGGL(attn_kernel, dim3(32, 32), dim3(256), 0, stream, Qb, Kb, Vb, XC);
  hipLaunchKernelGGL(gemm_wo, dim3(32, 16), dim3(256), 0, stream, XC, Wob, out);
}